// Round 8
// baseline (82.091 us; speedup 1.0000x reference)
//
#include <hip/hip_runtime.h>
#include <hip/hip_bf16.h>

// EnhancedBCMLayer: block-circulant matmul == dense GEMM
//   out = X (4096x2048 fp32) @ W^T (2048x2048) + b, fp32 out
//   W[f*16+t][g*16+u] = iv[f, g, (t-u)&15]
// Round-4 verified skeleton (BM=256 x BN=128 x BK=64, grid 256, 8 waves 4Mx2N,
// per-wave 64x64, 16x16x32 MFMA, ping-pong frag sets, 2 barriers/tile) with
// fused A-conversion: fp32 X -> regs (issued 1 tile early) -> f2bf pack ->
// swizzled ds_write into 2-slot A buffer. B: GLD bf16 W into 3-slot rotation.
// All waits FIFO-derived; no drain of fresh loads. T1+T2+T5.

#define M_DIM 4096
#define N_DIM 2048
#define K_DIM 2048
#define BK 64
#define NT (K_DIM / BK)   // 32 K-tiles

// LDS map (bytes): A slot a (a=0,1): a*32768, [256 rows][128 B]
//                  B slot s (s=0,1,2): 65536 + s*16384, [128 rows][128 B]
#define ABUF(a) ((a) * 32768)
#define BBUF(s) (65536 + (s) * 16384)

typedef __attribute__((ext_vector_type(8))) short bf16x8;
typedef __attribute__((ext_vector_type(4))) float f32x4;

typedef const __attribute__((address_space(1))) void gvoid_t;
typedef __attribute__((address_space(3))) void lvoid_t;

#define FENCE asm volatile("" ::: "memory")
#define BAR()  do { FENCE; __builtin_amdgcn_s_barrier(); FENCE; } while (0)
#define GLD(src, dst) __builtin_amdgcn_global_load_lds((gvoid_t*)(src), (lvoid_t*)(dst), 16, 0, 0)

// B staging: 2 GLDs cover 128 rows x 64 k
#define STAGE_B(dst, src) (GLD((src) + 0 * 64 * K_DIM, (dst) + 0),     \
                           GLD((src) + 1 * 64 * K_DIM, (dst) + 8192))

// fp32 -> bf16 RNE
__device__ __forceinline__ unsigned int f2bf(float f) {
  unsigned int u = __float_as_uint(f);
  return (u + 0x7fffu + ((u >> 16) & 1u)) >> 16;
}

// ---------------- prologue kernel: expand iv -> dense bf16 W [N][K] ----------------
__global__ __launch_bounds__(256) void prep_kernel(const float* __restrict__ iv,
                                                   unsigned short* __restrict__ W) {
  int idx = blockIdx.x * 256 + threadIdx.x;   // one per 8 weights
  int o  = idx >> 8;
  int i0 = (idx & 255) * 8;
  int f = o >> 4, t = o & 15;
  int g = i0 >> 4, u0 = i0 & 15;
  const float* row = iv + (f * 128 + g) * 16;
  unsigned int p[4];
#pragma unroll
  for (int j = 0; j < 4; ++j) {
    unsigned int lo = f2bf(row[(t - (u0 + 2 * j + 0)) & 15]);
    unsigned int hi = f2bf(row[(t - (u0 + 2 * j + 1)) & 15]);
    p[j] = lo | (hi << 16);
  }
  ((uint4*)W)[idx] = make_uint4(p[0], p[1], p[2], p[3]);
}

// ---------------- main GEMM ----------------
__global__ __launch_bounds__(512, 2) void gemm_bias_kernel(const float* __restrict__ X,
                                                           const unsigned short* __restrict__ B,
                                                           const float* __restrict__ bias,
                                                           float* __restrict__ C) {
  __shared__ char lds[112 * 1024];   // 64 KB A (2 slots) + 48 KB B (3 slots)

  const int tid = threadIdx.x;
  const int l   = tid & 63;
  const int w   = tid >> 6;       // wave 0..7
  const int wm  = w >> 1;         // wave M 0..3 (64 rows each)
  const int wn  = w & 1;          // wave N 0..1 (64 cols each)

  // T1: XCD-aware bijective swizzle (grid=256, 256%8==0)
  const int orig = blockIdx.x;
  const int swz  = (orig & 7) * 32 + (orig >> 3);
  const int bm   = swz >> 4;      // 0..15
  const int bn   = swz & 15;      // 0..15

  f32x4 acc[4][4] = {};

  // ---- A fused staging: lane covers rows j*64 + w*8 + (l>>3), k-slot l&7 (8 bf16) ----
  const int arow = w * 8 + (l >> 3);                 // row within j-group
  const int ks   = l & 7;
  const float* Afp = X + (size_t)(bm * 256 + arow) * K_DIM + ks * 8;
  // swizzled LDS write byte: slot ks ^ (row&7), row&7 == (l>>3)&7; + j*8192 + ABUF
  const int awbyte = arow * 128 + ((ks ^ ((l >> 3) & 7)) * 16);

  // ---- B staging (inverse-swizzled global source, linear LDS dest) ----
  const int srow  = w * 8 + (l >> 3);
  const int sslot = (l & 7) ^ ((l >> 3) & 7);
  const unsigned short* Bsrc0 = B + (size_t)(bn * 128 + srow) * K_DIM + sslot * 8;

  // ---- ds_read frag addresses (T2 swizzled) ----
  const int fr = l & 15;
  const int rxor = (l & 7) << 4;                        // (row&7)<<4
  const int aRow0 = (wm * 64 + fr) * 128;               // + m*2048 bytes
  const int bRow0 = (wn * 64 + fr) * 128;               // + n*2048 bytes
  const int swzcol0 = (0 * 64 + (l >> 4) * 16) ^ rxor;  // K 0..31
  const int swzcol1 = (1 * 64 + (l >> 4) * 16) ^ rxor;  // K 32..63

  // ping-pong fragment sets + one in-flight fp32 A tile
  bf16x8 fa0[4], fb0[4], fa1[4], fb1[4];
  float4 av[4][2];

#define LDA(SA, SB, AB, BS, SWZ)                                        \
  do {                                                                  \
    const char* Ab_ = lds + ABUF(AB);                                   \
    const char* Bb_ = lds + BBUF(BS);                                   \
    _Pragma("unroll")                                                   \
    for (int m = 0; m < 4; ++m)                                         \
      SA[m] = *(const bf16x8*)(Ab_ + aRow0 + m * 2048 + (SWZ));         \
    _Pragma("unroll")                                                   \
    for (int n = 0; n < 4; ++n)                                         \
      SB[n] = *(const bf16x8*)(Bb_ + bRow0 + n * 2048 + (SWZ));         \
  } while (0)

#define ALOAD(T)                                                        \
  do {                                                                  \
    _Pragma("unroll")                                                   \
    for (int j = 0; j < 4; ++j) {                                       \
      av[j][0] = *(const float4*)(Afp + (size_t)j * 64 * K_DIM + (T) * BK + 0); \
      av[j][1] = *(const float4*)(Afp + (size_t)j * 64 * K_DIM + (T) * BK + 4); \
    }                                                                   \
  } while (0)

#define AWRITE(AB)                                                      \
  do {                                                                  \
    char* dst_ = lds + ABUF(AB);                                        \
    _Pragma("unroll")                                                   \
    for (int j = 0; j < 4; ++j) {                                       \
      uint4 u_;                                                         \
      u_.x = f2bf(av[j][0].x) | (f2bf(av[j][0].y) << 16);               \
      u_.y = f2bf(av[j][0].z) | (f2bf(av[j][0].w) << 16);               \
      u_.z = f2bf(av[j][1].x) | (f2bf(av[j][1].y) << 16);               \
      u_.w = f2bf(av[j][1].z) | (f2bf(av[j][1].w) << 16);               \
      *(uint4*)(dst_ + j * 8192 + awbyte) = u_;                         \
    }                                                                   \
  } while (0)

#define MM(SA, SB, CNT)                                                 \
  do {                                                                  \
    asm volatile("s_waitcnt lgkmcnt(" #CNT ")" ::: "memory");           \
    __builtin_amdgcn_sched_barrier(0);                                  \
    __builtin_amdgcn_s_setprio(1);                                      \
    _Pragma("unroll")                                                   \
    for (int m = 0; m < 4; ++m)                                         \
      _Pragma("unroll")                                                 \
      for (int n = 0; n < 4; ++n)                                       \
        acc[m][n] = __builtin_amdgcn_mfma_f32_16x16x32_bf16(SA[m], SB[n], acc[m][n], 0, 0, 0); \
    __builtin_amdgcn_s_setprio(0);                                      \
    __builtin_amdgcn_sched_barrier(0);                                  \
  } while (0)

  // Steady-state tile t (ACUR=t&1, AOTH=(t+1)&1; B slots c=t%3, n=(t+1)%3, s=(t+2)%3):
  // P0: vmcnt(2)  [FIFO: Aload(t+1)x8 drained, B(t+2)x2 stay]
  //     AWRITE(t+1 -> AOTH) [4 ds_writes]
  //     LDA set1 (A:ACUR, B:slot c) [8 reads]
  //     MM set0 lgkm(8)  [queue 8 old reads+4 writes+8 new = 20 -> drains old reads AND writes]
  //     BAR  [A(t+1) writes now visible to all]
  // P1: vmcnt(0)  [only B(t+1)x2 pending, issued a full tile ago -> free]
  //     LDA set0 (A:AOTH, B:slot n) [8 reads]
  //     ALOAD(t+2) [8 vm]  then STAGE_B(t+2 -> slot s) [2 vm]
  //     MM set1 lgkm(8)  [queue set1x8 + set0x8 -> drains set1]
  //     BAR
#define BODY(T, ACUR, AOTH, BSC, BSN, BSS)                              \
  do {                                                                  \
    asm volatile("s_waitcnt vmcnt(2)" ::: "memory");                    \
    AWRITE(AOTH);                                                       \
    LDA(fa1, fb1, ACUR, BSC, swzcol1);                                  \
    MM(fa0, fb0, 8);                                                    \
    BAR();                                                              \
    asm volatile("s_waitcnt vmcnt(0)" ::: "memory");                    \
    LDA(fa0, fb0, AOTH, BSN, swzcol0);                                  \
    ALOAD((T) + 2);                                                     \
    STAGE_B(lds + BBUF(BSS) + w * 1024, Bsrc0 + ((T) + 2) * BK);        \
    MM(fa1, fb1, 8);                                                    \
    BAR();                                                              \
  } while (0)

  // ---- prologue ----
  ALOAD(0);
  AWRITE(0);                       // compiler inserts vmcnt for av deps
  ALOAD(1);                        // av(1), consumed at tile-0 P0
  STAGE_B(lds + BBUF(0) + w * 1024, Bsrc0 + 0 * BK);
  STAGE_B(lds + BBUF(1) + w * 1024, Bsrc0 + 1 * BK);
  asm volatile("s_waitcnt lgkmcnt(0)" ::: "memory");   // A(0) ds_writes done
  asm volatile("s_waitcnt vmcnt(2)" ::: "memory");     // [Al(1)x8, B0x2, B1x2] -> B0 landed, B1 stays
  BAR();
  LDA(fa0, fb0, 0, 0, swzcol0);    // set0(tile 0)

  // ---- main loop: tiles 0..29, unroll x6 (A parity x B slot rotation) ----
  for (int t = 0; t < NT - 2; t += 6) {
    BODY(t + 0, 0, 1, 0, 1, 2);
    BODY(t + 1, 1, 0, 1, 2, 0);
    BODY(t + 2, 0, 1, 2, 0, 1);
    BODY(t + 3, 1, 0, 0, 1, 2);
    BODY(t + 4, 0, 1, 1, 2, 0);
    BODY(t + 5, 1, 0, 2, 0, 1);
  }

  // ---- tile 30 (CUR=A0, slots c=0, n=1; no ALOAD(32)/STAGE_B(32)) ----
  asm volatile("s_waitcnt vmcnt(2)" ::: "memory");   // [Al(31)x8, B(31)x2] -> drains Al(31)
  AWRITE(1);                                         // A(31) -> slot A1
  LDA(fa1, fb1, 0, 0, swzcol1);
  MM(fa0, fb0, 8);
  BAR();
  asm volatile("s_waitcnt vmcnt(0)" ::: "memory");   // B(31) landed
  LDA(fa0, fb0, 1, 1, swzcol0);
  MM(fa1, fb1, 8);
  BAR();
  // ---- tile 31 ----
  LDA(fa1, fb1, 1, 1, swzcol1);
  MM(fa0, fb0, 8);
  MM(fa1, fb1, 0);

  // ---- epilogue: C/D layout col=lane&15, row=(lane>>4)*4+reg ----
  const int row0 = bm * 256 + wm * 64 + (l >> 4) * 4;
  const int col0 = bn * 128 + wn * 64 + (l & 15);
#pragma unroll
  for (int n = 0; n < 4; ++n) {
    float bv = bias[col0 + n * 16];
#pragma unroll
    for (int m = 0; m < 4; ++m) {
#pragma unroll
      for (int j = 0; j < 4; ++j) {
        C[(size_t)(row0 + m * 16 + j) * N_DIM + (col0 + n * 16)] = acc[m][n][j] + bv;
      }
    }
  }
#undef BODY
#undef MM
#undef AWRITE
#undef ALOAD
#undef LDA
}

// ---------------- fallback (ws too small): direct fp32 ----------------
__global__ __launch_bounds__(256) void fallback_kernel(const float* __restrict__ x,
                                                       const float* __restrict__ iv,
                                                       const float* __restrict__ b,
                                                       float* __restrict__ out) {
  int idx = blockIdx.x * 256 + threadIdx.x;
  int Bn = idx >> 11, o = idx & 2047;
  int f = o >> 4, t = o & 15;
  const float* xr = x + (size_t)Bn * 2048;
  float acc = 0.f;
  for (int g = 0; g < 128; ++g) {
    const float* pr = iv + (f * 128 + g) * 16;
    const float* xg = xr + g * 16;
#pragma unroll
    for (int s = 0; s < 16; ++s) acc += pr[s] * xg[(t - s) & 15];
  }
  out[idx] = acc + b[o];
}

extern "C" void kernel_launch(void* const* d_in, const int* in_sizes, int n_in,
                              void* d_out, int out_size, void* d_ws, size_t ws_size,
                              hipStream_t stream) {
  const float* x    = (const float*)d_in[0];
  const float* iv   = (const float*)d_in[1];
  const float* bias = (const float*)d_in[2];
  float* out = (float*)d_out;

  const size_t w_bytes = (size_t)N_DIM * K_DIM * 2;   // 8 MB
  if (ws_size < w_bytes) {
    fallback_kernel<<<(M_DIM * N_DIM) / 256, 256, 0, stream>>>(x, iv, bias, out);
    return;
  }

  unsigned short* W = (unsigned short*)d_ws;

  prep_kernel<<<(N_DIM * K_DIM / 8) / 256, 256, 0, stream>>>(iv, W);   // 2048 blocks, ~9 MB
  gemm_bias_kernel<<<(M_DIM / 256) * (N_DIM / 128), 512, 0, stream>>>(x, W, bias, out);
}

// Round 9
// 55.507 us; speedup vs baseline: 1.4789x; 1.4789x over previous
//
#include <hip/hip_runtime.h>
#include <hip/hip_bf16.h>

// EnhancedBCMLayer: block-circulant matmul == dense GEMM
//   out = X (4096x2048) @ W^T (2048x2048) + b, fp32 out
//   W[f*16+t][g*16+u] = iv[f, g, (t-u)&15]
// Round-4 skeleton (best: GEMM ~39us): BM=256 x BN=128 x BK=64, grid 256,
// 8 waves (4M x 2N), per-wave 64x64, 16x16x32 MFMA, 3 combined LDS buffers,
// cross-phase register ping-pong, lgkm(8), T1+T2+T5.
// ONE change vs round 4: B staged THREE tiles ahead (STAGE_B(t+3) into buf
// (t+3)%3's B-part) + vmcnt(4)->vmcnt(6) at P0. Gives B-GLD ~3 phases of
// flight (W is 8MB > 4MB/XCD L2 -> some B loads ride LLC/HBM ~900cy; the old
// 1-phase flight stalled every P0).

#define M_DIM 4096
#define N_DIM 2048
#define K_DIM 2048
#define BK 64
#define NT (K_DIM / BK)   // 32 K-tiles
#define BUFSZ 49152       // 48 KB: A [256 rows][128B] + B [128 rows][128B] at +32768

typedef __attribute__((ext_vector_type(8))) short bf16x8;
typedef __attribute__((ext_vector_type(4))) float f32x4;

typedef const __attribute__((address_space(1))) void gvoid_t;
typedef __attribute__((address_space(3))) void lvoid_t;

#define FENCE asm volatile("" ::: "memory")
#define BAR()  do { FENCE; __builtin_amdgcn_s_barrier(); FENCE; } while (0)
#define GLD(src, dst) __builtin_amdgcn_global_load_lds((gvoid_t*)(src), (lvoid_t*)(dst), 16, 0, 0)

// issue-order matters for vmcnt counting: A = 4 GLD, B = 2 GLD
#define STAGE_A(dst, src) (GLD((src) + 0 * 64 * K_DIM, (dst) + 0),     \
                           GLD((src) + 1 * 64 * K_DIM, (dst) + 8192),  \
                           GLD((src) + 2 * 64 * K_DIM, (dst) + 16384), \
                           GLD((src) + 3 * 64 * K_DIM, (dst) + 24576))
#define STAGE_B(dst, src) (GLD((src) + 0 * 64 * K_DIM, (dst) + 0),     \
                           GLD((src) + 1 * 64 * K_DIM, (dst) + 8192))

// fp32 -> bf16 RNE
__device__ __forceinline__ unsigned int f2bf(float f) {
  unsigned int u = __float_as_uint(f);
  return (u + 0x7fffu + ((u >> 16) & 1u)) >> 16;
}

// ---------------- fused prologue: cvt X -> bf16  |  expand iv -> dense bf16 W [N][K] ----------------
__global__ __launch_bounds__(256) void prep_kernel(const float* __restrict__ x,
                                                   const float* __restrict__ iv,
                                                   unsigned short* __restrict__ xb,
                                                   unsigned short* __restrict__ W) {
  int b = blockIdx.x;
  if (b < (M_DIM * K_DIM / 8) / 256) {
    int idx = b * 256 + threadIdx.x;          // one per 8 floats
    const float4* x4 = (const float4*)x;
    float4 a = x4[idx * 2 + 0];
    float4 c = x4[idx * 2 + 1];
    uint4 o;
    o.x = f2bf(a.x) | (f2bf(a.y) << 16);
    o.y = f2bf(a.z) | (f2bf(a.w) << 16);
    o.z = f2bf(c.x) | (f2bf(c.y) << 16);
    o.w = f2bf(c.z) | (f2bf(c.w) << 16);
    ((uint4*)xb)[idx] = o;
  } else {
    int idx = (b - (M_DIM * K_DIM / 8) / 256) * 256 + threadIdx.x;  // one per 8 weights
    int o  = idx >> 8;             // W row 0..2047
    int i0 = (idx & 255) * 8;      // col start
    int f = o >> 4, t = o & 15;
    int g = i0 >> 4, u0 = i0 & 15;
    const float* row = iv + (f * 128 + g) * 16;
    unsigned int p[4];
#pragma unroll
    for (int j = 0; j < 4; ++j) {
      unsigned int lo = f2bf(row[(t - (u0 + 2 * j + 0)) & 15]);
      unsigned int hi = f2bf(row[(t - (u0 + 2 * j + 1)) & 15]);
      p[j] = lo | (hi << 16);
    }
    ((uint4*)W)[idx] = make_uint4(p[0], p[1], p[2], p[3]);
  }
}

// ---------------- main GEMM ----------------
// LDS: 3 combined buffers of 48 KB: buf c at c*BUFSZ, A-part [256][128B],
// B-part at +32768 [128][128B]. Tile t: A in buf t%3 A-part, B in buf t%3 B-part.
// XOR-swizzle byte ^= (row&7)<<4 on both the GLD global source and the ds_read col.
__global__ __launch_bounds__(512, 2) void gemm_bias_kernel(const unsigned short* __restrict__ A,
                                                           const unsigned short* __restrict__ B,
                                                           const float* __restrict__ bias,
                                                           float* __restrict__ C) {
  __shared__ char lds[3 * BUFSZ];   // 144 KB

  const int tid = threadIdx.x;
  const int l   = tid & 63;
  const int w   = tid >> 6;       // wave 0..7
  const int wm  = w >> 1;         // wave row 0..3 (64 rows each)
  const int wn  = w & 1;          // wave col 0..1 (64 cols each)

  // T1: XCD-aware bijective swizzle (grid=256, 256%8==0)
  const int orig = blockIdx.x;
  const int swz  = (orig & 7) * 32 + (orig >> 3);
  const int bm   = swz >> 4;      // 0..15  (M tile)
  const int bn   = swz & 15;      // 0..15  (N tile)

  f32x4 acc[4][4] = {};

  // ---- staging addresses (inverse-swizzled global source, linear LDS dest) ----
  const int srow  = w * 8 + (l >> 3);               // 0..63
  const int sslot = (l & 7) ^ ((l >> 3) & 7);       // pre-swizzled K-slot
  const unsigned short* Asrc0 = A + (size_t)(bm * 256 + srow) * K_DIM + sslot * 8;
  const unsigned short* Bsrc0 = B + (size_t)(bn * 128 + srow) * K_DIM + sslot * 8;

  // ---- ds_read addresses (T2 swizzled) ----
  const int fr = l & 15;                            // fragment row within 16
  const int rxor = (l & 7) << 4;                    // (row&7)<<4
  const int aRow0 = (wm * 64 + fr) * 128;           // byte row base, + m*2048
  const int bRow0 = (wn * 64 + fr) * 128;           // + n*2048
  const int swzcol0 = (0 * 64 + (l >> 4) * 16) ^ rxor;  // K 0..31
  const int swzcol1 = (1 * 64 + (l >> 4) * 16) ^ rxor;  // K 32..63

  // ping-pong fragment sets: set0 consumed by P0-MFMA, set1 by P1-MFMA
  bf16x8 fa0[4], fb0[4], fa1[4], fb1[4];

#define LDA(SA, SB, BUF, SWZ)                                           \
  do {                                                                  \
    const char* Ab_ = lds + (BUF) * BUFSZ;                              \
    const char* Bb_ = Ab_ + 32768;                                      \
    _Pragma("unroll")                                                   \
    for (int m = 0; m < 4; ++m)                                         \
      SA[m] = *(const bf16x8*)(Ab_ + aRow0 + m * 2048 + (SWZ));         \
    _Pragma("unroll")                                                   \
    for (int n = 0; n < 4; ++n)                                         \
      SB[n] = *(const bf16x8*)(Bb_ + bRow0 + n * 2048 + (SWZ));         \
  } while (0)

#define MM(SA, SB, CNT)                                                 \
  do {                                                                  \
    asm volatile("s_waitcnt lgkmcnt(" #CNT ")" ::: "memory");           \
    __builtin_amdgcn_sched_barrier(0);                                  \
    __builtin_amdgcn_s_setprio(1);                                      \
    _Pragma("unroll")                                                   \
    for (int m = 0; m < 4; ++m)                                         \
      _Pragma("unroll")                                                 \
      for (int n = 0; n < 4; ++n)                                       \
        acc[m][n] = __builtin_amdgcn_mfma_f32_16x16x32_bf16(SA[m], SB[n], acc[m][n], 0, 0, 0); \
    __builtin_amdgcn_s_setprio(0);                                      \
    __builtin_amdgcn_sched_barrier(0);                                  \
  } while (0)

  // Steady-state tile t (CUR=t%3, NXT=(t+1)%3, STG=(t+2)%3; B stage slot = CUR=(t+3)%3):
  // P0: LDA set1 (tile t hi-K) | STAGE_A(t+2)->STG.A | MFMA set0 (lgkm 8)
  //     vmcnt(6): FIFO [B(t+1)2, A(t+1)4, B(t+2)2, A(t+2)4]=12 -> drains
  //     A(t+1)+B(t+1) (flights: A 2 phases, B 3 phases); BAR
  // P1: LDA set0 (tile t+1 from NXT) | STAGE_B(t+3)->CUR.B | MFMA set1 (lgkm 8); BAR
  //     (slot-reuse safe: CUR.B's reads at t.P0 are lgkm-drained by this MM
  //      before the new GLD write can land)
#define BODY(T, CUR, NXT, STG)                                          \
  do {                                                                  \
    LDA(fa1, fb1, CUR, swzcol1);                                        \
    STAGE_A(lds + (STG) * BUFSZ + w * 1024, Asrc0 + ((T) + 2) * BK);    \
    MM(fa0, fb0, 8);                                                    \
    asm volatile("s_waitcnt vmcnt(6)" ::: "memory");                    \
    BAR();                                                              \
    LDA(fa0, fb0, NXT, swzcol0);                                        \
    STAGE_B(lds + (CUR) * BUFSZ + 32768 + w * 1024, Bsrc0 + ((T) + 3) * BK); \
    MM(fa1, fb1, 8);                                                    \
    BAR();                                                              \
  } while (0)

  // ---- prologue: A(0),B(0),A(1),B(1),B(2) (issue order fixes FIFO) ----
  STAGE_A(lds + 0 * BUFSZ + w * 1024, Asrc0 + 0 * BK);
  STAGE_B(lds + 0 * BUFSZ + 32768 + w * 1024, Bsrc0 + 0 * BK);
  STAGE_A(lds + 1 * BUFSZ + w * 1024, Asrc0 + 1 * BK);
  STAGE_B(lds + 1 * BUFSZ + 32768 + w * 1024, Bsrc0 + 1 * BK);
  STAGE_B(lds + 2 * BUFSZ + 32768 + w * 1024, Bsrc0 + 2 * BK);
  asm volatile("s_waitcnt vmcnt(8)" ::: "memory");  // 14-8=6 oldest: A(0)4+B(0)2 landed
  BAR();
  LDA(fa0, fb0, 0, swzcol0);                        // set0 = tile 0 lo-K

  // ---- main loop: bodies 0..26 (9 iterations, buf indices compile-time) ----
  for (int t = 0; t < 27; t += 3) {
    BODY(t + 0, 0, 1, 2);
    BODY(t + 1, 1, 2, 0);
    BODY(t + 2, 2, 0, 1);
  }
  // ---- peeled tail ----
  BODY(27, 0, 1, 2);      // stages A(29), B(30)
  BODY(28, 1, 2, 0);      // stages A(30), B(31)
  // body 29 (CUR=2, NXT=0, STG=1): stages A(31); NO STAGE_B
  LDA(fa1, fb1, 2, swzcol1);
  STAGE_A(lds + 1 * BUFSZ + w * 1024, Asrc0 + 31 * BK);
  MM(fa0, fb0, 8);
  asm volatile("s_waitcnt vmcnt(6)" ::: "memory");  // [B(30)2,A(30)4,B(31)2,A(31)4] -> drains B30,A30
  BAR();
  LDA(fa0, fb0, 0, swzcol0);
  MM(fa1, fb1, 8);
  BAR();
  // body 30 (CUR=0, NXT=1): no staging
  LDA(fa1, fb1, 0, swzcol1);
  MM(fa0, fb0, 8);
  asm volatile("s_waitcnt vmcnt(0)" ::: "memory");  // B(31), A(31) landed
  BAR();
  LDA(fa0, fb0, 1, swzcol0);
  MM(fa1, fb1, 8);
  // body 31 (buf 1): no barriers needed
  LDA(fa1, fb1, 1, swzcol1);
  MM(fa0, fb0, 8);
  MM(fa1, fb1, 0);

  // ---- epilogue: C/D layout col=lane&15, row=(lane>>4)*4+reg ----
  const int row0 = bm * 256 + wm * 64 + (l >> 4) * 4;
  const int col0 = bn * 128 + wn * 64 + (l & 15);
#pragma unroll
  for (int n = 0; n < 4; ++n) {
    float bv = bias[col0 + n * 16];
#pragma unroll
    for (int m = 0; m < 4; ++m) {
#pragma unroll
      for (int j = 0; j < 4; ++j) {
        C[(size_t)(row0 + m * 16 + j) * N_DIM + (col0 + n * 16)] = acc[m][n][j] + bv;
      }
    }
  }
#undef BODY
#undef MM
#undef LDA
}

// ---------------- fallback (ws too small): direct fp32 ----------------
__global__ __launch_bounds__(256) void fallback_kernel(const float* __restrict__ x,
                                                       const float* __restrict__ iv,
                                                       const float* __restrict__ b,
                                                       float* __restrict__ out) {
  int idx = blockIdx.x * 256 + threadIdx.x;
  int Bn = idx >> 11, o = idx & 2047;
  int f = o >> 4, t = o & 15;
  const float* xr = x + (size_t)Bn * 2048;
  float acc = 0.f;
  for (int g = 0; g < 128; ++g) {
    const float* pr = iv + (f * 128 + g) * 16;
    const float* xg = xr + g * 16;
#pragma unroll
    for (int s = 0; s < 16; ++s) acc += pr[s] * xg[(t - s) & 15];
  }
  out[idx] = acc + b[o];
}

extern "C" void kernel_launch(void* const* d_in, const int* in_sizes, int n_in,
                              void* d_out, int out_size, void* d_ws, size_t ws_size,
                              hipStream_t stream) {
  const float* x    = (const float*)d_in[0];
  const float* iv   = (const float*)d_in[1];
  const float* bias = (const float*)d_in[2];
  float* out = (float*)d_out;

  const size_t xb_bytes = (size_t)M_DIM * K_DIM * 2;
  const size_t w_bytes  = (size_t)N_DIM * K_DIM * 2;
  if (ws_size < xb_bytes + w_bytes) {
    fallback_kernel<<<(M_DIM * N_DIM) / 256, 256, 0, stream>>>(x, iv, bias, out);
    return;
  }

  unsigned short* xb = (unsigned short*)d_ws;
  unsigned short* W  = xb + (size_t)M_DIM * K_DIM;

  const int cvt_blocks = (M_DIM * K_DIM / 8) / 256;   // 4096
  const int bw_blocks  = (N_DIM * K_DIM / 8) / 256;   // 2048
  prep_kernel<<<cvt_blocks + bw_blocks, 256, 0, stream>>>(x, iv, xb, W);

  gemm_bias_kernel<<<(M_DIM / 256) * (N_DIM / 128), 512, 0, stream>>>(xb, W, bias, out);
}